// Round 1
// baseline (3771.149 us; speedup 1.0000x reference)
//
#include <hip/hip_runtime.h>
#include <math.h>

// Problem constants (match reference)
#define N_NODES 50000
#define N_EDGES 800000
#define RELS    3
#define HID     64
#define S_SEEDS 8192
#define OUT_COLS 321   // 1 (pred_missing) + 320 (pred_feat)
#define S_CH    1024   // seed-chunk for the 2048-wide hidden layer

// ---------------------------------------------------------------------------
// Generic register-tiled GEMM: C = act(A @ B + bias) [+ noise]
// A: M x K row-major (lda), batched by sAb
// B: K x Nc row-major (ldb), batched by sBb
// C: M x Nc with row stride ldc, batched by sCb
// act: 0=none 1=relu 2=leaky(0.01) 3=tanh
// noise (nullable): added after activation, indexed [gr*ldc + gc] layout-compatible
// ---------------------------------------------------------------------------
template<int TM, int TN>
__global__ __launch_bounds__(256) void gemm_act(
    const float* __restrict__ A, long long sAb, int lda,
    const float* __restrict__ B, long long sBb, int ldb,
    const float* __restrict__ bias, long long sBiasb,
    float* __restrict__ C, long long sCb, int ldc,
    const float* __restrict__ noise,
    int M, int Nc, int K, int act)
{
    constexpr int BM = 16 * TM, BN = 16 * TN, BK = 16;
    __shared__ float As[BK][BM + 1];
    __shared__ float Bs[BK][BN + 1];

    const int r = blockIdx.z;
    A += (long long)r * sAb;
    B += (long long)r * sBb;
    C += (long long)r * sCb;
    if (bias) bias += (long long)r * sBiasb;

    const int tx = threadIdx.x, ty = threadIdx.y;
    const int tid = ty * 16 + tx;
    const int row0 = blockIdx.y * BM;
    const int col0 = blockIdx.x * BN;

    float acc[TM][TN];
#pragma unroll
    for (int i = 0; i < TM; i++)
#pragma unroll
        for (int j = 0; j < TN; j++) acc[i][j] = 0.f;

    for (int k0 = 0; k0 < K; k0 += BK) {
        // A tile (BM x BK) -> As[k][m]; consecutive tid -> consecutive k (coalesced)
        for (int idx = tid; idx < BM * BK; idx += 256) {
            int m = idx / BK, kk = idx % BK;
            int gr = row0 + m, gk = k0 + kk;
            As[kk][m] = (gr < M && gk < K) ? A[(long long)gr * lda + gk] : 0.f;
        }
        // B tile (BK x BN) -> Bs[k][n]; consecutive tid -> consecutive n (coalesced)
        for (int idx = tid; idx < BK * BN; idx += 256) {
            int kk = idx / BN, n = idx % BN;
            int gk = k0 + kk, gc = col0 + n;
            Bs[kk][n] = (gk < K && gc < Nc) ? B[(long long)gk * ldb + gc] : 0.f;
        }
        __syncthreads();
#pragma unroll
        for (int kk = 0; kk < BK; kk++) {
            float a[TM], b[TN];
#pragma unroll
            for (int i = 0; i < TM; i++) a[i] = As[kk][ty * TM + i];
#pragma unroll
            for (int j = 0; j < TN; j++) b[j] = Bs[kk][tx * TN + j];
#pragma unroll
            for (int i = 0; i < TM; i++)
#pragma unroll
                for (int j = 0; j < TN; j++)
                    acc[i][j] += a[i] * b[j];
        }
        __syncthreads();
    }

#pragma unroll
    for (int i = 0; i < TM; i++) {
        int gr = row0 + ty * TM + i;
        if (gr >= M) continue;
#pragma unroll
        for (int j = 0; j < TN; j++) {
            int gc = col0 + tx * TN + j;
            if (gc >= Nc) continue;
            float v = acc[i][j];
            if (bias) v += bias[gc];
            if (act == 1)      v = fmaxf(v, 0.f);
            else if (act == 2) v = (v > 0.f) ? v : 0.01f * v;
            else if (act == 3) v = tanhf(v);
            if (noise) v += noise[(long long)gr * ldc + gc];
            C[(long long)gr * ldc + gc] = v;
        }
    }
}

template<int TM, int TN>
static void launch_gemm(hipStream_t st,
                        const float* A, long long sA, int lda,
                        const float* B, long long sB, int ldb,
                        const float* bias, long long sBias,
                        float* C, long long sC, int ldc,
                        const float* noise,
                        int M, int Nc, int K, int act, int batch)
{
    dim3 grid((Nc + 16 * TN - 1) / (16 * TN), (M + 16 * TM - 1) / (16 * TM), batch);
    dim3 block(16, 16, 1);
    gemm_act<TM, TN><<<grid, block, 0, st>>>(A, sA, lda, B, sB, ldb, bias, sBias,
                                             C, sC, ldc, noise, M, Nc, K, act);
}

// ---------------------------------------------------------------------------
// Graph kernels
// ---------------------------------------------------------------------------
__global__ void deg_count_kernel(const int* __restrict__ dst, float* __restrict__ deg, int E)
{
    int e = blockIdx.x * blockDim.x + threadIdx.x;
    if (e < E) atomicAdd(&deg[dst[e]], 1.0f);
}

__global__ void invdeg_kernel(float* __restrict__ deg, int n)
{
    int i = blockIdx.x * blockDim.x + threadIdx.x;
    if (i < n) deg[i] = 1.0f / fmaxf(deg[i], 1.0f);
}

// One wave of 64 lanes per edge (4 edges per 256-thread block).
// acc[dst] += Wh[src] * invdeg[dst]; edges with dst >= maxDst skipped.
__global__ void scatter_kernel(const float* __restrict__ Wh,     // N x 64 (this relation)
                               const int* __restrict__ src,
                               const int* __restrict__ dst,
                               const float* __restrict__ invdeg, // N (this relation)
                               float* __restrict__ acc,          // maxDst x 64
                               int E, int maxDst)
{
    int lane = threadIdx.x;                       // 0..63
    int e = blockIdx.x * blockDim.y + threadIdx.y;
    if (e >= E) return;
    int d = dst[e];
    if (d >= maxDst) return;
    int s = src[e];
    float v = Wh[(long long)s * HID + lane] * invdeg[d];
    atomicAdd(&acc[(long long)d * HID + lane], v);
}

__global__ void bias_relu_kernel(const float* __restrict__ acc,
                                 const float* __restrict__ b,
                                 float* __restrict__ out, long long total)
{
    long long i = (long long)blockIdx.x * blockDim.x + threadIdx.x;
    if (i < total) out[i] = fmaxf(acc[i] + b[i & 63], 0.f);
}

// ---------------------------------------------------------------------------
extern "C" void kernel_launch(void* const* d_in, const int* in_sizes, int n_in,
                              void* d_out, int out_size, void* d_ws, size_t ws_size,
                              hipStream_t stream)
{
    const float* x     = (const float*)d_in[0];
    const float* noise = (const float*)d_in[1];
    // d_in[2] = seeds: only its shape matters (S=8192); unused.
    const int* srcs[RELS] = { (const int*)d_in[3], (const int*)d_in[5], (const int*)d_in[7] };
    const int* dsts[RELS] = { (const int*)d_in[4], (const int*)d_in[6], (const int*)d_in[8] };
    const float* Wc1  = (const float*)d_in[9];
    const float* bc1  = (const float*)d_in[10];
    const float* Wc2  = (const float*)d_in[11];
    const float* bc2  = (const float*)d_in[12];
    const float* Wlin = (const float*)d_in[13];
    const float* blin = (const float*)d_in[14];
    const float* dW1  = (const float*)d_in[15];
    const float* db1  = (const float*)d_in[16];
    const float* dW2  = (const float*)d_in[17];
    const float* db2  = (const float*)d_in[18];
    const float* dW3  = (const float*)d_in[19];
    const float* db3  = (const float*)d_in[20];
    const float* fW1  = (const float*)d_in[21];
    const float* fb1  = (const float*)d_in[22];
    const float* fW2  = (const float*)d_in[23];
    const float* fb2  = (const float*)d_in[24];
    const float* fW3  = (const float*)d_in[25];
    const float* fb3  = (const float*)d_in[26];
    float* out = (float*)d_out;
    float* w   = (float*)d_ws;

    // Workspace layout (floats). Total ~23.5M floats = ~94 MB.
    float* invdeg = w;                                   // 3*N
    float* Wh     = w + 150016;                          // 3*N*64  = 9,600,000
    float* z1     = Wh;                                  // alias: 3*S*256 = 6,291,456
    float* z2d    = Wh + (long long)RELS * S_SEEDS * 256;// alias: 3*S*32 = 786,432 (fits in Wh region)
    float* acc    = Wh + 9600000LL;                      // N*64   = 3,200,000
    float* h1     = acc + 3200000LL;                     // N*64   = 3,200,000
    float* h2s    = h1 + 3200000LL;                      // S*64   = 524,288
    float* hs     = h2s + 524288LL;                      // S*64   = 524,288
    float* z2f    = hs + 524288LL;                       // 3*S_CH*2048 = 6,291,456

    // ---- degrees (shared by both conv layers) ----
    hipMemsetAsync(invdeg, 0, (size_t)RELS * N_NODES * sizeof(float), stream);
    for (int r = 0; r < RELS; r++)
        deg_count_kernel<<<(N_EDGES + 255) / 256, 256, 0, stream>>>(dsts[r], invdeg + (long long)r * N_NODES, N_EDGES);
    invdeg_kernel<<<(RELS * N_NODES + 255) / 256, 256, 0, stream>>>(invdeg, RELS * N_NODES);

    // ---- conv layer 1 ----
    // Wh[r] = x @ Wc1[r]  (no bias; bias added post-aggregation)
    launch_gemm<4, 4>(stream, x, 0, HID, Wc1, (long long)HID * HID, HID,
                      nullptr, 0, Wh, (long long)N_NODES * HID, HID, nullptr,
                      N_NODES, HID, HID, 0, RELS);
    hipMemsetAsync(acc, 0, (size_t)N_NODES * HID * sizeof(float), stream);
    for (int r = 0; r < RELS; r++)
        scatter_kernel<<<(N_EDGES + 3) / 4, dim3(64, 4, 1), 0, stream>>>(
            Wh + (long long)r * N_NODES * HID, srcs[r], dsts[r],
            invdeg + (long long)r * N_NODES, acc, N_EDGES, N_NODES);
    bias_relu_kernel<<<(N_NODES * HID + 255) / 256, 256, 0, stream>>>(acc, bc1, h1, (long long)N_NODES * HID);

    // ---- conv layer 2 (output only needed for rows < S) ----
    launch_gemm<4, 4>(stream, h1, 0, HID, Wc2, (long long)HID * HID, HID,
                      nullptr, 0, Wh, (long long)N_NODES * HID, HID, nullptr,
                      N_NODES, HID, HID, 0, RELS);
    hipMemsetAsync(acc, 0, (size_t)S_SEEDS * HID * sizeof(float), stream);
    for (int r = 0; r < RELS; r++)
        scatter_kernel<<<(N_EDGES + 3) / 4, dim3(64, 4, 1), 0, stream>>>(
            Wh + (long long)r * N_NODES * HID, srcs[r], dsts[r],
            invdeg + (long long)r * N_NODES, acc, N_EDGES, S_SEEDS);
    bias_relu_kernel<<<(S_SEEDS * HID + 255) / 256, 256, 0, stream>>>(acc, bc2, h2s, (long long)S_SEEDS * HID);

    // ---- hs = leaky(h2s @ Wlin + blin) + noise[:S] ----
    launch_gemm<4, 4>(stream, h2s, 0, HID, Wlin, 0, HID, blin, 0,
                      hs, 0, HID, noise, S_SEEDS, HID, HID, 2, 1);

    // ---- d-branch: pred_missing ----
    launch_gemm<4, 4>(stream, hs, 0, HID, dW1, 64LL * 256, 256, db1, 256,
                      z1, (long long)S_SEEDS * 256, 256, nullptr, S_SEEDS, 256, HID, 2, RELS);
    launch_gemm<4, 4>(stream, z1, (long long)S_SEEDS * 256, 256, dW2, 256LL * 32, 32, db2, 32,
                      z2d, (long long)S_SEEDS * 32, 32, nullptr, S_SEEDS, 32, 256, 2, RELS);
    launch_gemm<2, 2>(stream, z2d, (long long)S_SEEDS * 32, 32, dW3, 32LL, 1, db3, 1,
                      out, (long long)S_SEEDS * OUT_COLS, OUT_COLS, nullptr, S_SEEDS, 1, 32, 1, RELS);

    // ---- f-branch: pred_feat ----
    launch_gemm<4, 4>(stream, hs, 0, HID, fW1, 64LL * 256, 256, fb1, 256,
                      z1, (long long)S_SEEDS * 256, 256, nullptr, S_SEEDS, 256, HID, 1, RELS);
    for (int c = 0; c < S_SEEDS / S_CH; c++) {
        long long s0 = (long long)c * S_CH;
        // z2f = relu(z1[:, s0:s0+S_CH, :] @ fW2 + fb2)   (3, S_CH, 2048)
        launch_gemm<4, 4>(stream, z1 + s0 * 256, (long long)S_SEEDS * 256, 256,
                          fW2, 256LL * 2048, 2048, fb2, 2048,
                          z2f, (long long)S_CH * 2048, 2048, nullptr, S_CH, 2048, 256, 1, RELS);
        // pred_feat chunk = tanh(z2f @ fW3 + fb3) -> out[r, s0+s, 1:321]
        launch_gemm<2, 2>(stream, z2f, (long long)S_CH * 2048, 2048,
                          fW3, 2048LL * 320, 320, fb3, 320,
                          out + s0 * OUT_COLS + 1, (long long)S_SEEDS * OUT_COLS, OUT_COLS, nullptr,
                          S_CH, 320, 2048, 3, RELS);
    }
}

// Round 3
// 1699.233 us; speedup vs baseline: 2.2193x; 2.2193x over previous
//
#include <hip/hip_runtime.h>
#include <math.h>

// Problem constants (match reference)
#define N_NODES 50000
#define N_EDGES 800000
#define RELS    3
#define HID     64
#define S_SEEDS 8192
#define OUT_COLS 321   // 1 (pred_missing) + 320 (pred_feat)
#define S_CH    2048   // seed-chunk for the 2048-wide hidden layer (bf16 z2 chunk)

typedef __attribute__((ext_vector_type(8))) short v8s;   // 8 bf16 in 4 VGPRs
typedef __attribute__((ext_vector_type(4))) float v4f;   // MFMA accumulator

__device__ __forceinline__ unsigned short f32_to_bf16(float f) {
    unsigned int u = __float_as_uint(f);
    unsigned int r = u + 0x7FFFu + ((u >> 16) & 1u);   // round-to-nearest-even
    return (unsigned short)(r >> 16);
}

// ---------------------------------------------------------------------------
// Generic register-tiled f32 GEMM: C = act(A @ B + bias) [+ noise]
// (graph trunk + d-branch; the heavy f-branch uses MFMA below)
// ---------------------------------------------------------------------------
template<int TM, int TN>
__global__ __launch_bounds__(256) void gemm_act(
    const float* __restrict__ A, long long sAb, int lda,
    const float* __restrict__ B, long long sBb, int ldb,
    const float* __restrict__ bias, long long sBiasb,
    float* __restrict__ C, long long sCb, int ldc,
    const float* __restrict__ noise,
    int M, int Nc, int K, int act)
{
    constexpr int BM = 16 * TM, BN = 16 * TN, BK = 16;
    __shared__ float As[BK][BM + 1];
    __shared__ float Bs[BK][BN + 1];

    const int r = blockIdx.z;
    A += (long long)r * sAb;
    B += (long long)r * sBb;
    C += (long long)r * sCb;
    if (bias) bias += (long long)r * sBiasb;

    const int tx = threadIdx.x, ty = threadIdx.y;
    const int tid = ty * 16 + tx;
    const int row0 = blockIdx.y * BM;
    const int col0 = blockIdx.x * BN;

    float acc[TM][TN];
#pragma unroll
    for (int i = 0; i < TM; i++)
#pragma unroll
        for (int j = 0; j < TN; j++) acc[i][j] = 0.f;

    for (int k0 = 0; k0 < K; k0 += BK) {
        for (int idx = tid; idx < BM * BK; idx += 256) {
            int m = idx / BK, kk = idx % BK;
            int gr = row0 + m, gk = k0 + kk;
            As[kk][m] = (gr < M && gk < K) ? A[(long long)gr * lda + gk] : 0.f;
        }
        for (int idx = tid; idx < BK * BN; idx += 256) {
            int kk = idx / BN, n = idx % BN;
            int gk = k0 + kk, gc = col0 + n;
            Bs[kk][n] = (gk < K && gc < Nc) ? B[(long long)gk * ldb + gc] : 0.f;
        }
        __syncthreads();
#pragma unroll
        for (int kk = 0; kk < BK; kk++) {
            float a[TM], b[TN];
#pragma unroll
            for (int i = 0; i < TM; i++) a[i] = As[kk][ty * TM + i];
#pragma unroll
            for (int j = 0; j < TN; j++) b[j] = Bs[kk][tx * TN + j];
#pragma unroll
            for (int i = 0; i < TM; i++)
#pragma unroll
                for (int j = 0; j < TN; j++)
                    acc[i][j] += a[i] * b[j];
        }
        __syncthreads();
    }

#pragma unroll
    for (int i = 0; i < TM; i++) {
        int gr = row0 + ty * TM + i;
        if (gr >= M) continue;
#pragma unroll
        for (int j = 0; j < TN; j++) {
            int gc = col0 + tx * TN + j;
            if (gc >= Nc) continue;
            float v = acc[i][j];
            if (bias) v += bias[gc];
            if (act == 1)      v = fmaxf(v, 0.f);
            else if (act == 2) v = (v > 0.f) ? v : 0.01f * v;
            else if (act == 3) v = tanhf(v);
            if (noise) v += noise[(long long)gr * ldc + gc];
            C[(long long)gr * ldc + gc] = v;
        }
    }
}

template<int TM, int TN>
static void launch_gemm(hipStream_t st,
                        const float* A, long long sA, int lda,
                        const float* B, long long sB, int ldb,
                        const float* bias, long long sBias,
                        float* C, long long sC, int ldc,
                        const float* noise,
                        int M, int Nc, int K, int act, int batch)
{
    dim3 grid((Nc + 16 * TN - 1) / (16 * TN), (M + 16 * TM - 1) / (16 * TM), batch);
    dim3 block(16, 16, 1);
    gemm_act<TM, TN><<<grid, block, 0, st>>>(A, sA, lda, B, sB, ldb, bias, sBias,
                                             C, sC, ldc, noise, M, Nc, K, act);
}

// ---------------------------------------------------------------------------
// bf16 MFMA GEMM: C = act(A @ Bt^T + bias)
// A : M x K bf16 row-major (lda), batch stride sAb (elements)
// Bt: N x K bf16 (B pre-transposed), batch stride sBb
// C : f32 or bf16, row stride ldc, batch stride sCb
// Block 256 = 4 waves; tile 128x128; BK=32.
// Staging: 2 threads per row, 16 elements (32 B) each => full 64 B row. [R2 fix:
// previous version staged 8 elements per thread, leaving half the LDS row
// uninitialized -> NaN garbage into MFMA.]
// ACT: 0=none 1=relu 3=tanh
// ---------------------------------------------------------------------------
template<int ACT, bool OUT_BF16>
__global__ __launch_bounds__(256) void gemm_mfma_bf16(
    const unsigned short* __restrict__ A, long long sAb, int lda,
    const unsigned short* __restrict__ Bt, long long sBb,
    const float* __restrict__ bias, long long sBiasb,
    void* __restrict__ Cv, long long sCb, int ldc,
    int M, int Nc, int K)
{
    __shared__ __align__(16) unsigned short As[128][40];
    __shared__ __align__(16) unsigned short Bs[128][40];

    const int r = blockIdx.z;
    A  += (long long)r * sAb;
    Bt += (long long)r * sBb;
    const float* brow = bias ? bias + (long long)r * sBiasb : nullptr;

    const int tid  = threadIdx.x;
    const int wave = tid >> 6, lane = tid & 63;
    const int quad = lane >> 4, l16 = lane & 15;
    const int wrow = (wave >> 1) * 64, wcol = (wave & 1) * 64;
    const int row0 = blockIdx.y * 128, col0 = blockIdx.x * 128;

    v4f acc[4][4] = {};

    const int srow = tid >> 1;            // 0..127
    const int ecol = (tid & 1) * 16;      // element offset 0 or 16 (each thread stages 16 bf16 = 32 B)

    for (int k0 = 0; k0 < K; k0 += 32) {
        int gr = row0 + srow;
        int4 a0 = make_int4(0, 0, 0, 0), a1 = make_int4(0, 0, 0, 0);
        if (gr < M) {
            const unsigned short* ap = A + (long long)gr * lda + k0 + ecol;
            a0 = *(const int4*)(ap);
            a1 = *(const int4*)(ap + 8);
        }
        *(int4*)(&As[srow][ecol])     = a0;
        *(int4*)(&As[srow][ecol + 8]) = a1;

        int gn = col0 + srow;
        int4 b0 = make_int4(0, 0, 0, 0), b1 = make_int4(0, 0, 0, 0);
        if (gn < Nc) {
            const unsigned short* bp = Bt + (long long)gn * K + k0 + ecol;
            b0 = *(const int4*)(bp);
            b1 = *(const int4*)(bp + 8);
        }
        *(int4*)(&Bs[srow][ecol])     = b0;
        *(int4*)(&Bs[srow][ecol + 8]) = b1;
        __syncthreads();

        v8s af[4], bfr[4];
#pragma unroll
        for (int i = 0; i < 4; i++)
            af[i] = *(const v8s*)(&As[wrow + i * 16 + l16][quad * 8]);
#pragma unroll
        for (int j = 0; j < 4; j++)
            bfr[j] = *(const v8s*)(&Bs[wcol + j * 16 + l16][quad * 8]);
#pragma unroll
        for (int i = 0; i < 4; i++)
#pragma unroll
            for (int j = 0; j < 4; j++)
                acc[i][j] = __builtin_amdgcn_mfma_f32_16x16x32_bf16(af[i], bfr[j], acc[i][j], 0, 0, 0);
        __syncthreads();
    }

    float* Cf = (float*)Cv + (long long)r * sCb;
    unsigned short* Cb = (unsigned short*)Cv + (long long)r * sCb;
#pragma unroll
    for (int i = 0; i < 4; i++) {
#pragma unroll
        for (int j = 0; j < 4; j++) {
            int gc = col0 + wcol + j * 16 + l16;
            if (gc >= Nc) continue;
            float bv = brow ? brow[gc] : 0.f;
#pragma unroll
            for (int t = 0; t < 4; t++) {
                int gr = row0 + wrow + i * 16 + quad * 4 + t;
                if (gr >= M) continue;
                float v = acc[i][j][t] + bv;
                if (ACT == 1)      v = fmaxf(v, 0.f);
                else if (ACT == 3) v = tanhf(v);
                if (OUT_BF16) Cb[(long long)gr * ldc + gc] = f32_to_bf16(v);
                else          Cf[(long long)gr * ldc + gc] = v;
            }
        }
    }
}

// ---------------------------------------------------------------------------
// Conversion / transpose prep kernels
// ---------------------------------------------------------------------------
__global__ void cvt_f32_bf16_kernel(const float* __restrict__ src,
                                    unsigned short* __restrict__ dst, long long n)
{
    long long i = (long long)blockIdx.x * blockDim.x + threadIdx.x;
    if (i < n) dst[i] = f32_to_bf16(src[i]);
}

// src: (R, K, N) f32 row-major -> dst: (R, N, K) bf16
__global__ void cvt_transpose_bf16_kernel(const float* __restrict__ src,
                                          unsigned short* __restrict__ dst,
                                          int K, int N, long long total)
{
    long long i = (long long)blockIdx.x * blockDim.x + threadIdx.x;
    if (i >= total) return;
    long long kn = (long long)K * N;
    int r = (int)(i / kn);
    long long rem = i - (long long)r * kn;
    int k = (int)(rem / N), n = (int)(rem - (long long)k * N);
    dst[(long long)r * kn + (long long)n * K + k] = f32_to_bf16(src[i]);
}

// ---------------------------------------------------------------------------
// Graph kernels
// ---------------------------------------------------------------------------
__global__ void deg_count_kernel(const int* __restrict__ dst, float* __restrict__ deg, int E)
{
    int e = blockIdx.x * blockDim.x + threadIdx.x;
    if (e < E) atomicAdd(&deg[dst[e]], 1.0f);
}

__global__ void invdeg_kernel(float* __restrict__ deg, int n)
{
    int i = blockIdx.x * blockDim.x + threadIdx.x;
    if (i < n) deg[i] = 1.0f / fmaxf(deg[i], 1.0f);
}

__global__ void scatter_kernel(const float* __restrict__ Wh,
                               const int* __restrict__ src,
                               const int* __restrict__ dst,
                               const float* __restrict__ invdeg,
                               float* __restrict__ acc,
                               int E, int maxDst)
{
    int lane = threadIdx.x;
    int e = blockIdx.x * blockDim.y + threadIdx.y;
    if (e >= E) return;
    int d = dst[e];
    if (d >= maxDst) return;
    int s = src[e];
    float v = Wh[(long long)s * HID + lane] * invdeg[d];
    atomicAdd(&acc[(long long)d * HID + lane], v);
}

__global__ void bias_relu_kernel(const float* __restrict__ acc,
                                 const float* __restrict__ b,
                                 float* __restrict__ out, long long total)
{
    long long i = (long long)blockIdx.x * blockDim.x + threadIdx.x;
    if (i < total) out[i] = fmaxf(acc[i] + b[i & 63], 0.f);
}

// ---------------------------------------------------------------------------
extern "C" void kernel_launch(void* const* d_in, const int* in_sizes, int n_in,
                              void* d_out, int out_size, void* d_ws, size_t ws_size,
                              hipStream_t stream)
{
    const float* x     = (const float*)d_in[0];
    const float* noise = (const float*)d_in[1];
    // d_in[2] = seeds: only its shape matters (S=8192); unused.
    const int* srcs[RELS] = { (const int*)d_in[3], (const int*)d_in[5], (const int*)d_in[7] };
    const int* dsts[RELS] = { (const int*)d_in[4], (const int*)d_in[6], (const int*)d_in[8] };
    const float* Wc1  = (const float*)d_in[9];
    const float* bc1  = (const float*)d_in[10];
    const float* Wc2  = (const float*)d_in[11];
    const float* bc2  = (const float*)d_in[12];
    const float* Wlin = (const float*)d_in[13];
    const float* blin = (const float*)d_in[14];
    const float* dW1  = (const float*)d_in[15];
    const float* db1  = (const float*)d_in[16];
    const float* dW2  = (const float*)d_in[17];
    const float* db2  = (const float*)d_in[18];
    const float* dW3  = (const float*)d_in[19];
    const float* db3  = (const float*)d_in[20];
    const float* fW1  = (const float*)d_in[21];
    const float* fb1  = (const float*)d_in[22];
    const float* fW2  = (const float*)d_in[23];
    const float* fb2  = (const float*)d_in[24];
    const float* fW3  = (const float*)d_in[25];
    const float* fb3  = (const float*)d_in[26];
    float* out = (float*)d_out;
    float* w   = (float*)d_ws;

    // ---- workspace layout (float offsets; ~80 MB total) ----
    float* invdeg = w;                                   // 3*N = 150,000 (+pad)
    float* Wh     = w + 150016;                          // 3*N*64 = 9,600,000 (conv phase)
    float* z1     = Wh;                                  // alias post-conv: d-branch f32, 3*S*256 = 6,291,456
    unsigned short* z1bf = (unsigned short*)(Wh + 6291456);   // 3*S*256 bf16 (3,145,728 f) -> end 9,587,200 < 9.6M
    float* acc    = w + 9750016;                         // N*64 = 3,200,000
    float* h1     = acc + 3200000LL;                     // N*64 = 3,200,000
    unsigned short* z2bf = (unsigned short*)acc;         // alias post-conv: 3*S_CH*2048 bf16 = 6,291,456 f < 6.4M
    float* h2s    = h1 + 3200000LL;                      // S*64 = 524,288
    float* hs     = h2s + 524288LL;                      // S*64 = 524,288
    float* z2d    = hs + 524288LL;                       // 3*S*32 = 786,432
    unsigned short* hsbf  = (unsigned short*)(z2d + 786432LL);    // S*64 bf16 = 262,144 f
    unsigned short* fW1bt = (unsigned short*)(z2d + 1048576LL);   // 3*256*64 bf16 = 24,576 f
    unsigned short* fW2bt = (unsigned short*)(z2d + 1073152LL);   // 3*2048*256 bf16 = 786,432 f
    unsigned short* fW3bt = (unsigned short*)(z2d + 1859584LL);   // 3*320*2048 bf16 = 983,040 f

    // ---- degrees (shared by both conv layers) ----
    hipMemsetAsync(invdeg, 0, (size_t)RELS * N_NODES * sizeof(float), stream);
    for (int r = 0; r < RELS; r++)
        deg_count_kernel<<<(N_EDGES + 255) / 256, 256, 0, stream>>>(dsts[r], invdeg + (long long)r * N_NODES, N_EDGES);
    invdeg_kernel<<<(RELS * N_NODES + 255) / 256, 256, 0, stream>>>(invdeg, RELS * N_NODES);

    // ---- conv layer 1 ----
    launch_gemm<4, 4>(stream, x, 0, HID, Wc1, (long long)HID * HID, HID,
                      nullptr, 0, Wh, (long long)N_NODES * HID, HID, nullptr,
                      N_NODES, HID, HID, 0, RELS);
    hipMemsetAsync(acc, 0, (size_t)N_NODES * HID * sizeof(float), stream);
    for (int r = 0; r < RELS; r++)
        scatter_kernel<<<(N_EDGES + 3) / 4, dim3(64, 4, 1), 0, stream>>>(
            Wh + (long long)r * N_NODES * HID, srcs[r], dsts[r],
            invdeg + (long long)r * N_NODES, acc, N_EDGES, N_NODES);
    bias_relu_kernel<<<(N_NODES * HID + 255) / 256, 256, 0, stream>>>(acc, bc1, h1, (long long)N_NODES * HID);

    // ---- conv layer 2 (only rows < S needed downstream) ----
    launch_gemm<4, 4>(stream, h1, 0, HID, Wc2, (long long)HID * HID, HID,
                      nullptr, 0, Wh, (long long)N_NODES * HID, HID, nullptr,
                      N_NODES, HID, HID, 0, RELS);
    hipMemsetAsync(acc, 0, (size_t)S_SEEDS * HID * sizeof(float), stream);
    for (int r = 0; r < RELS; r++)
        scatter_kernel<<<(N_EDGES + 3) / 4, dim3(64, 4, 1), 0, stream>>>(
            Wh + (long long)r * N_NODES * HID, srcs[r], dsts[r],
            invdeg + (long long)r * N_NODES, acc, N_EDGES, S_SEEDS);
    bias_relu_kernel<<<(S_SEEDS * HID + 255) / 256, 256, 0, stream>>>(acc, bc2, h2s, (long long)S_SEEDS * HID);

    // ---- hs = leaky(h2s @ Wlin + blin) + noise[:S] (f32) ----
    launch_gemm<4, 4>(stream, h2s, 0, HID, Wlin, 0, HID, blin, 0,
                      hs, 0, HID, noise, S_SEEDS, HID, HID, 2, 1);

    // ---- d-branch (f32, small): pred_missing -> out col 0 ----
    launch_gemm<4, 4>(stream, hs, 0, HID, dW1, 64LL * 256, 256, db1, 256,
                      z1, (long long)S_SEEDS * 256, 256, nullptr, S_SEEDS, 256, HID, 2, RELS);
    launch_gemm<4, 4>(stream, z1, (long long)S_SEEDS * 256, 256, dW2, 256LL * 32, 32, db2, 32,
                      z2d, (long long)S_SEEDS * 32, 32, nullptr, S_SEEDS, 32, 256, 2, RELS);
    launch_gemm<2, 2>(stream, z2d, (long long)S_SEEDS * 32, 32, dW3, 32LL, 1, db3, 1,
                      out, (long long)S_SEEDS * OUT_COLS, OUT_COLS, nullptr, S_SEEDS, 1, 32, 1, RELS);

    // ---- f-branch prep: bf16 conversions ----
    cvt_f32_bf16_kernel<<<(S_SEEDS * HID + 255) / 256, 256, 0, stream>>>(hs, hsbf, (long long)S_SEEDS * HID);
    cvt_transpose_bf16_kernel<<<(RELS * 64 * 256 + 255) / 256, 256, 0, stream>>>(fW1, fW1bt, 64, 256, (long long)RELS * 64 * 256);
    cvt_transpose_bf16_kernel<<<(RELS * 256 * 2048 + 255) / 256, 256, 0, stream>>>(fW2, fW2bt, 256, 2048, (long long)RELS * 256 * 2048);
    cvt_transpose_bf16_kernel<<<(RELS * 2048 * 320 + 255) / 256, 256, 0, stream>>>(fW3, fW3bt, 2048, 320, (long long)RELS * 2048 * 320);

    // ---- f-branch: z1bf = relu(hs @ fW1 + fb1)  (3, S, 256) bf16 ----
    {
        dim3 grid(256 / 128, S_SEEDS / 128, RELS);
        gemm_mfma_bf16<1, true><<<grid, 256, 0, stream>>>(
            hsbf, 0, HID, fW1bt, 256LL * 64, fb1, 256,
            z1bf, (long long)S_SEEDS * 256, 256, S_SEEDS, 256, HID);
    }
    // ---- f-branch main: chunked over S ----
    for (int c = 0; c < S_SEEDS / S_CH; c++) {
        long long s0 = (long long)c * S_CH;
        // z2bf = relu(z1bf[chunk] @ fW2 + fb2)  (3, S_CH, 2048) bf16
        dim3 g2(2048 / 128, S_CH / 128, RELS);
        gemm_mfma_bf16<1, true><<<g2, 256, 0, stream>>>(
            z1bf + s0 * 256, (long long)S_SEEDS * 256, 256,
            fW2bt, 2048LL * 256, fb2, 2048,
            z2bf, (long long)S_CH * 2048, 2048, S_CH, 2048, 256);
        // out[:, s0:s0+S_CH, 1:321] = tanh(z2bf @ fW3 + fb3)
        dim3 g3((320 + 127) / 128, S_CH / 128, RELS);
        gemm_mfma_bf16<3, false><<<g3, 256, 0, stream>>>(
            z2bf, (long long)S_CH * 2048, 2048,
            fW3bt, 320LL * 2048, fb3, 320,
            out + s0 * OUT_COLS + 1, (long long)S_SEEDS * OUT_COLS, OUT_COLS,
            S_CH, 320, 2048);
    }
}

// Round 4
// 1166.927 us; speedup vs baseline: 3.2317x; 1.4562x over previous
//
#include <hip/hip_runtime.h>
#include <math.h>

// Problem constants (match reference)
#define N_NODES 50000
#define N_EDGES 800000
#define RELS    3
#define HID     64
#define S_SEEDS 8192
#define OUT_COLS 321   // 1 (pred_missing) + 320 (pred_feat)
#define S_CH    2048   // seed-chunk for the 2048-wide f-branch hidden layer
#define NPITCH  50048  // per-relation pitch for counts/rowptr/cursor/invdeg
#define NB_SCAN 196    // ceil(50000/256)

typedef __attribute__((ext_vector_type(8))) short v8s;   // 8 bf16 in 4 VGPRs
typedef __attribute__((ext_vector_type(4))) float v4f;   // MFMA accumulator

__device__ __forceinline__ unsigned short f32_to_bf16(float f) {
    unsigned int u = __float_as_uint(f);
    unsigned int r = u + 0x7FFFu + ((u >> 16) & 1u);   // round-to-nearest-even
    return (unsigned short)(r >> 16);
}

// ---------------------------------------------------------------------------
// Generic register-tiled f32 GEMM: C = act(A @ B + bias) [+ noise]
// (trunk only: conv GEMMs + lin; heads use MFMA)
// ---------------------------------------------------------------------------
template<int TM, int TN>
__global__ __launch_bounds__(256) void gemm_act(
    const float* __restrict__ A, long long sAb, int lda,
    const float* __restrict__ B, long long sBb, int ldb,
    const float* __restrict__ bias, long long sBiasb,
    float* __restrict__ C, long long sCb, int ldc,
    const float* __restrict__ noise,
    int M, int Nc, int K, int act)
{
    constexpr int BM = 16 * TM, BN = 16 * TN, BK = 16;
    __shared__ float As[BK][BM + 1];
    __shared__ float Bs[BK][BN + 1];

    const int r = blockIdx.z;
    A += (long long)r * sAb;
    B += (long long)r * sBb;
    C += (long long)r * sCb;
    if (bias) bias += (long long)r * sBiasb;

    const int tx = threadIdx.x, ty = threadIdx.y;
    const int tid = ty * 16 + tx;
    const int row0 = blockIdx.y * BM;
    const int col0 = blockIdx.x * BN;

    float acc[TM][TN];
#pragma unroll
    for (int i = 0; i < TM; i++)
#pragma unroll
        for (int j = 0; j < TN; j++) acc[i][j] = 0.f;

    for (int k0 = 0; k0 < K; k0 += BK) {
        for (int idx = tid; idx < BM * BK; idx += 256) {
            int m = idx / BK, kk = idx % BK;
            int gr = row0 + m, gk = k0 + kk;
            As[kk][m] = (gr < M && gk < K) ? A[(long long)gr * lda + gk] : 0.f;
        }
        for (int idx = tid; idx < BK * BN; idx += 256) {
            int kk = idx / BN, n = idx % BN;
            int gk = k0 + kk, gc = col0 + n;
            Bs[kk][n] = (gk < K && gc < Nc) ? B[(long long)gk * ldb + gc] : 0.f;
        }
        __syncthreads();
#pragma unroll
        for (int kk = 0; kk < BK; kk++) {
            float a[TM], b[TN];
#pragma unroll
            for (int i = 0; i < TM; i++) a[i] = As[kk][ty * TM + i];
#pragma unroll
            for (int j = 0; j < TN; j++) b[j] = Bs[kk][tx * TN + j];
#pragma unroll
            for (int i = 0; i < TM; i++)
#pragma unroll
                for (int j = 0; j < TN; j++)
                    acc[i][j] += a[i] * b[j];
        }
        __syncthreads();
    }

#pragma unroll
    for (int i = 0; i < TM; i++) {
        int gr = row0 + ty * TM + i;
        if (gr >= M) continue;
#pragma unroll
        for (int j = 0; j < TN; j++) {
            int gc = col0 + tx * TN + j;
            if (gc >= Nc) continue;
            float v = acc[i][j];
            if (bias) v += bias[gc];
            if (act == 1)      v = fmaxf(v, 0.f);
            else if (act == 2) v = (v > 0.f) ? v : 0.01f * v;
            else if (act == 3) v = tanhf(v);
            if (noise) v += noise[(long long)gr * ldc + gc];
            C[(long long)gr * ldc + gc] = v;
        }
    }
}

template<int TM, int TN>
static void launch_gemm(hipStream_t st,
                        const float* A, long long sA, int lda,
                        const float* B, long long sB, int ldb,
                        const float* bias, long long sBias,
                        float* C, long long sC, int ldc,
                        const float* noise,
                        int M, int Nc, int K, int act, int batch)
{
    dim3 grid((Nc + 16 * TN - 1) / (16 * TN), (M + 16 * TM - 1) / (16 * TM), batch);
    dim3 block(16, 16, 1);
    gemm_act<TM, TN><<<grid, block, 0, st>>>(A, sA, lda, B, sB, ldb, bias, sBias,
                                             C, sC, ldc, noise, M, Nc, K, act);
}

// ---------------------------------------------------------------------------
// bf16 MFMA GEMM: C = act(A @ Bt^T + bias)
// A : M x K bf16 row-major (lda); Bt: N x K bf16 (B pre-transposed)
// Block 256 = 4 waves; tile 128x128; BK=32. Staging: 2 threads/row x 32 B.
// ACT: 0=none 1=relu 2=leaky(0.01) 3=tanh
// ---------------------------------------------------------------------------
template<int ACT, bool OUT_BF16>
__global__ __launch_bounds__(256) void gemm_mfma_bf16(
    const unsigned short* __restrict__ A, long long sAb, int lda,
    const unsigned short* __restrict__ Bt, long long sBb,
    const float* __restrict__ bias, long long sBiasb,
    void* __restrict__ Cv, long long sCb, int ldc,
    int M, int Nc, int K)
{
    __shared__ __align__(16) unsigned short As[128][40];
    __shared__ __align__(16) unsigned short Bs[128][40];

    const int r = blockIdx.z;
    A  += (long long)r * sAb;
    Bt += (long long)r * sBb;
    const float* brow = bias ? bias + (long long)r * sBiasb : nullptr;

    const int tid  = threadIdx.x;
    const int wave = tid >> 6, lane = tid & 63;
    const int quad = lane >> 4, l16 = lane & 15;
    const int wrow = (wave >> 1) * 64, wcol = (wave & 1) * 64;
    const int row0 = blockIdx.y * 128, col0 = blockIdx.x * 128;

    v4f acc[4][4] = {};

    const int srow = tid >> 1;            // 0..127
    const int ecol = (tid & 1) * 16;      // each thread stages 16 bf16 = 32 B

    for (int k0 = 0; k0 < K; k0 += 32) {
        int gr = row0 + srow;
        int4 a0 = make_int4(0, 0, 0, 0), a1 = make_int4(0, 0, 0, 0);
        if (gr < M) {
            const unsigned short* ap = A + (long long)gr * lda + k0 + ecol;
            a0 = *(const int4*)(ap);
            a1 = *(const int4*)(ap + 8);
        }
        *(int4*)(&As[srow][ecol])     = a0;
        *(int4*)(&As[srow][ecol + 8]) = a1;

        int gn = col0 + srow;
        int4 b0 = make_int4(0, 0, 0, 0), b1 = make_int4(0, 0, 0, 0);
        if (gn < Nc) {
            const unsigned short* bp = Bt + (long long)gn * K + k0 + ecol;
            b0 = *(const int4*)(bp);
            b1 = *(const int4*)(bp + 8);
        }
        *(int4*)(&Bs[srow][ecol])     = b0;
        *(int4*)(&Bs[srow][ecol + 8]) = b1;
        __syncthreads();

        v8s af[4], bfr[4];
#pragma unroll
        for (int i = 0; i < 4; i++)
            af[i] = *(const v8s*)(&As[wrow + i * 16 + l16][quad * 8]);
#pragma unroll
        for (int j = 0; j < 4; j++)
            bfr[j] = *(const v8s*)(&Bs[wcol + j * 16 + l16][quad * 8]);
#pragma unroll
        for (int i = 0; i < 4; i++)
#pragma unroll
            for (int j = 0; j < 4; j++)
                acc[i][j] = __builtin_amdgcn_mfma_f32_16x16x32_bf16(af[i], bfr[j], acc[i][j], 0, 0, 0);
        __syncthreads();
    }

    float* Cf = (float*)Cv + (long long)r * sCb;
    unsigned short* Cb = (unsigned short*)Cv + (long long)r * sCb;
#pragma unroll
    for (int i = 0; i < 4; i++) {
#pragma unroll
        for (int j = 0; j < 4; j++) {
            int gc = col0 + wcol + j * 16 + l16;
            if (gc >= Nc) continue;
            float bv = brow ? brow[gc] : 0.f;
#pragma unroll
            for (int t = 0; t < 4; t++) {
                int gr = row0 + wrow + i * 16 + quad * 4 + t;
                if (gr >= M) continue;
                float v = acc[i][j][t] + bv;
                if (ACT == 1)      v = fmaxf(v, 0.f);
                else if (ACT == 2) v = (v > 0.f) ? v : 0.01f * v;
                else if (ACT == 3) v = tanhf(v);
                if (OUT_BF16) Cb[(long long)gr * ldc + gc] = f32_to_bf16(v);
                else          Cf[(long long)gr * ldc + gc] = v;
            }
        }
    }
}

// ---------------------------------------------------------------------------
// Conversion / transpose prep kernels
// ---------------------------------------------------------------------------
__global__ void cvt_f32_bf16_kernel(const float* __restrict__ src,
                                    unsigned short* __restrict__ dst, long long n)
{
    long long i = (long long)blockIdx.x * blockDim.x + threadIdx.x;
    if (i < n) dst[i] = f32_to_bf16(src[i]);
}

// src: (R, K, N) f32 row-major -> dst: (R, N, K) bf16
__global__ void cvt_transpose_bf16_kernel(const float* __restrict__ src,
                                          unsigned short* __restrict__ dst,
                                          int K, int N, long long total)
{
    long long i = (long long)blockIdx.x * blockDim.x + threadIdx.x;
    if (i >= total) return;
    long long kn = (long long)K * N;
    int r = (int)(i / kn);
    long long rem = i - (long long)r * kn;
    int k = (int)(rem / N), n = (int)(rem - (long long)k * N);
    dst[(long long)r * kn + (long long)n * K + k] = f32_to_bf16(src[i]);
}

// ---------------------------------------------------------------------------
// CSR build: histogram -> block scan (3 kernels) -> cursor fill
// counts/rowptr/cursor/invdeg are (RELS, NPITCH); csr_src is (RELS, N_EDGES)
// ---------------------------------------------------------------------------
__global__ void hist_kernel(const int* __restrict__ dst, long long sDst,
                            int* __restrict__ counts)
{
    int rel = blockIdx.y;
    int e = blockIdx.x * blockDim.x + threadIdx.x;
    if (e < N_EDGES) atomicAdd(&counts[rel * NPITCH + dst[rel * sDst + e]], 1);
}

__global__ void scan1_kernel(const int* __restrict__ counts,
                             int* __restrict__ rowptr, int* __restrict__ partials)
{
    __shared__ int sd[256];
    int rel = blockIdx.y, t = threadIdx.x;
    int i = blockIdx.x * 256 + t;
    int v = (i < N_NODES) ? counts[rel * NPITCH + i] : 0;
    sd[t] = v; __syncthreads();
    for (int off = 1; off < 256; off <<= 1) {
        int x = (t >= off) ? sd[t - off] : 0;
        __syncthreads();
        sd[t] += x;
        __syncthreads();
    }
    if (i < N_NODES) rowptr[rel * NPITCH + i] = sd[t] - v;   // local exclusive
    if (t == 255) partials[rel * 256 + blockIdx.x] = sd[255];
}

__global__ void scan2_kernel(int* __restrict__ partials)
{
    __shared__ int sd[256];
    int rel = blockIdx.y, t = threadIdx.x;
    int v = (t < NB_SCAN) ? partials[rel * 256 + t] : 0;
    sd[t] = v; __syncthreads();
    for (int off = 1; off < 256; off <<= 1) {
        int x = (t >= off) ? sd[t - off] : 0;
        __syncthreads();
        sd[t] += x;
        __syncthreads();
    }
    if (t < NB_SCAN) partials[rel * 256 + t] = sd[t] - v;    // exclusive
}

__global__ void scan3_kernel(const int* __restrict__ counts,
                             int* __restrict__ rowptr, const int* __restrict__ partials,
                             int* __restrict__ cursor, float* __restrict__ invdeg)
{
    int rel = blockIdx.y, t = threadIdx.x;
    int i = blockIdx.x * 256 + t;
    if (i < N_NODES) {
        int rp = rowptr[rel * NPITCH + i] + partials[rel * 256 + blockIdx.x];
        rowptr[rel * NPITCH + i] = rp;
        cursor[rel * NPITCH + i] = rp;
        int c = counts[rel * NPITCH + i];
        invdeg[rel * NPITCH + i] = 1.0f / fmaxf((float)c, 1.0f);
    }
    if (i == 0) rowptr[rel * NPITCH + N_NODES] = N_EDGES;
}

__global__ void fill_kernel(const int* __restrict__ src, const int* __restrict__ dst,
                            long long sEdge, int* __restrict__ cursor,
                            int* __restrict__ csr_src)
{
    int rel = blockIdx.y;
    int e = blockIdx.x * blockDim.x + threadIdx.x;
    if (e >= N_EDGES) return;
    int d = dst[rel * sEdge + e];
    int pos = atomicAdd(&cursor[rel * NPITCH + d], 1);
    csr_src[(long long)rel * N_EDGES + pos] = src[rel * sEdge + e];
}

// ---------------------------------------------------------------------------
// CSR gather: one wave per (node, relation); lane = feature.
// agg[d][r*64 + lane] = invdeg[r][d] * sum_{edges r: s->d} feat[s][lane]
// ---------------------------------------------------------------------------
__global__ __launch_bounds__(256) void gather_kernel(
    const float* __restrict__ feat,       // (*, 64)
    const int* __restrict__ rowptr,       // (RELS, NPITCH)
    const int* __restrict__ csr_src,      // (RELS, N_EDGES)
    const float* __restrict__ invdeg,     // (RELS, NPITCH)
    float* __restrict__ agg,              // (M, 192)
    int M)
{
    int w = (blockIdx.x * 256 + threadIdx.x) >> 6;
    int lane = threadIdx.x & 63;
    if (w >= M * RELS) return;
    int r = w % RELS, d = w / RELS;
    int rp0 = rowptr[r * NPITCH + d];
    int rp1 = rowptr[r * NPITCH + d + 1];
    const int* cp = csr_src + (long long)r * N_EDGES;
    float acc0 = 0.f, acc1 = 0.f;
    int i = rp0;
    for (; i + 1 < rp1; i += 2) {
        int s0 = cp[i], s1 = cp[i + 1];
        acc0 += feat[(long long)s0 * HID + lane];
        acc1 += feat[(long long)s1 * HID + lane];
    }
    if (i < rp1) acc0 += feat[(long long)cp[i] * HID + lane];
    agg[(long long)d * (RELS * HID) + r * HID + lane] =
        (acc0 + acc1) * invdeg[r * NPITCH + d];
}

// ---------------------------------------------------------------------------
// d-branch final head: out[r,s,0] = relu(z2d[r,s,:] . dW3[r] + db3[r])
// ---------------------------------------------------------------------------
__global__ void dhead_kernel(const float* __restrict__ z2d,
                             const float* __restrict__ dW3,
                             const float* __restrict__ db3,
                             float* __restrict__ out)
{
    int idx = blockIdx.x * blockDim.x + threadIdx.x;
    if (idx >= RELS * S_SEEDS) return;
    int r = idx / S_SEEDS;
    const float* zp = z2d + (long long)idx * 32;
    const float* wp = dW3 + r * 32;
    float acc = db3[r];
#pragma unroll
    for (int k = 0; k < 32; k++) acc += zp[k] * wp[k];
    out[(long long)idx * OUT_COLS] = fmaxf(acc, 0.f);
}

// ---------------------------------------------------------------------------
extern "C" void kernel_launch(void* const* d_in, const int* in_sizes, int n_in,
                              void* d_out, int out_size, void* d_ws, size_t ws_size,
                              hipStream_t stream)
{
    const float* x     = (const float*)d_in[0];
    const float* noise = (const float*)d_in[1];
    // d_in[2] = seeds: only its shape matters (S=8192); unused.
    const int* srcs[RELS] = { (const int*)d_in[3], (const int*)d_in[5], (const int*)d_in[7] };
    const int* dsts[RELS] = { (const int*)d_in[4], (const int*)d_in[6], (const int*)d_in[8] };
    const float* Wc1  = (const float*)d_in[9];   // (3,64,64) == stacked (192,64)
    const float* bc1  = (const float*)d_in[10];
    const float* Wc2  = (const float*)d_in[11];
    const float* bc2  = (const float*)d_in[12];
    const float* Wlin = (const float*)d_in[13];
    const float* blin = (const float*)d_in[14];
    const float* dW1  = (const float*)d_in[15];
    const float* db1  = (const float*)d_in[16];
    const float* dW2  = (const float*)d_in[17];
    const float* db2  = (const float*)d_in[18];
    const float* dW3  = (const float*)d_in[19];
    const float* db3  = (const float*)d_in[20];
    const float* fW1  = (const float*)d_in[21];
    const float* fb1  = (const float*)d_in[22];
    const float* fW2  = (const float*)d_in[23];
    const float* fb2  = (const float*)d_in[24];
    const float* fW3  = (const float*)d_in[25];
    const float* fb3  = (const float*)d_in[26];
    float* out = (float*)d_out;
    float* w   = (float*)d_ws;

    // ---- workspace layout (4-byte units; ~82 MB total) ----
    int*   counts  = (int*)w;                             // 3*NPITCH = 150,144
    int*   rowptr  = (int*)(w + 150144);                  // 150,144
    int*   cursor  = (int*)(w + 300288);                  // 150,144
    int*   partials= (int*)(w + 450432);                  // 768
    float* invdeg  = w + 451200;                          // 150,144
    int*   csr_src = (int*)(w + 601344);                  // 3*800,000 = 2,400,000
    float* aggx    = w + 3001344;                         // 50000*192 = 9,600,000
    unsigned short* z2bf = (unsigned short*)aggx;         // alias (6,291,456 f) - after aggx dead
    float* h1      = w + 12601344;                        // 50000*64 = 3,200,000
    unsigned short* z1bf = (unsigned short*)h1;           // alias (3,145,728 f) - after h1 dead
    float* agg2    = w + 15801344;                        // 8192*192 = 1,572,864
    float* z2d     = agg2;                                // alias (786,432 f) - after agg2 dead
    float* h2s     = w + 17374208;                        // 524,288
    float* hs      = w + 17898496;                        // 524,288
    unsigned short* hsbf  = (unsigned short*)(w + 18422784); // 262,144 f
    unsigned short* fW1bt = (unsigned short*)(w + 18684928); // 24,576 f
    unsigned short* fW2bt = (unsigned short*)(w + 18709504); // 786,432 f
    unsigned short* fW3bt = (unsigned short*)(w + 19495936); // 983,040 f
    unsigned short* dW1bt = (unsigned short*)(w + 20478976); // 24,576 f
    unsigned short* dW2bt = (unsigned short*)(w + 20503552); // 12,288 f

    // ---- CSR build (shared by both conv layers) ----
    hipMemsetAsync(counts, 0, (size_t)RELS * NPITCH * sizeof(int), stream);
    {
        dim3 ge((N_EDGES + 255) / 256, RELS);
        // edge arrays are separate inputs; pass via per-relation loop (sEdge=0)
        for (int r = 0; r < RELS; r++) {
            dim3 g1((N_EDGES + 255) / 256, 1);
            hipLaunchKernelGGL(hist_kernel, g1, dim3(256), 0, stream,
                               dsts[r], 0LL, counts + r * NPITCH - 0);
            // note: counts pointer offset by rel via blockIdx.y==0 trick:
        }
    }
    // The loop above launched with rel=blockIdx.y==0; adjust: we offset counts per call.
    // (hist_kernel indexes counts[rel*NPITCH + ...] with rel=0, and dst[0*sDst + e].)

    {
        dim3 gs1(NB_SCAN, RELS);
        scan1_kernel<<<gs1, 256, 0, stream>>>(counts, rowptr, partials);
        dim3 gs2(1, RELS);
        scan2_kernel<<<gs2, 256, 0, stream>>>(partials);
        dim3 gs3(NB_SCAN, RELS);
        scan3_kernel<<<gs3, 256, 0, stream>>>(counts, rowptr, partials, cursor, invdeg);
    }
    for (int r = 0; r < RELS; r++) {
        dim3 gf((N_EDGES + 255) / 256, 1);
        fill_kernel<<<gf, 256, 0, stream>>>(srcs[r], dsts[r], 0LL,
                                            cursor + r * NPITCH,
                                            csr_src + (long long)r * N_EDGES);
    }

    // ---- conv layer 1: gather x -> aggx (50000x192), GEMM -> h1 ----
    {
        int waves = N_NODES * RELS;
        gather_kernel<<<(waves * 64 + 255) / 256, 256, 0, stream>>>(
            x, rowptr, csr_src, invdeg, aggx, N_NODES);
    }
    launch_gemm<4, 4>(stream, aggx, 0, RELS * HID, Wc1, 0, HID, bc1, 0,
                      h1, 0, HID, nullptr, N_NODES, HID, RELS * HID, 1, 1);

    // ---- conv layer 2: gather h1 (d < S only) -> agg2 (8192x192), GEMM -> h2s ----
    {
        int waves = S_SEEDS * RELS;
        gather_kernel<<<(waves * 64 + 255) / 256, 256, 0, stream>>>(
            h1, rowptr, csr_src, invdeg, agg2, S_SEEDS);
    }
    launch_gemm<4, 4>(stream, agg2, 0, RELS * HID, Wc2, 0, HID, bc2, 0,
                      h2s, 0, HID, nullptr, S_SEEDS, HID, RELS * HID, 1, 1);

    // ---- hs = leaky(h2s @ Wlin + blin) + noise[:S] ----
    launch_gemm<4, 4>(stream, h2s, 0, HID, Wlin, 0, HID, blin, 0,
                      hs, 0, HID, noise, S_SEEDS, HID, HID, 2, 1);

    // ---- bf16 prep ----
    cvt_f32_bf16_kernel<<<(S_SEEDS * HID + 255) / 256, 256, 0, stream>>>(hs, hsbf, (long long)S_SEEDS * HID);
    cvt_transpose_bf16_kernel<<<(RELS * 64 * 256 + 255) / 256, 256, 0, stream>>>(dW1, dW1bt, 64, 256, (long long)RELS * 64 * 256);
    cvt_transpose_bf16_kernel<<<(RELS * 256 * 32 + 255) / 256, 256, 0, stream>>>(dW2, dW2bt, 256, 32, (long long)RELS * 256 * 32);
    cvt_transpose_bf16_kernel<<<(RELS * 64 * 256 + 255) / 256, 256, 0, stream>>>(fW1, fW1bt, 64, 256, (long long)RELS * 64 * 256);
    cvt_transpose_bf16_kernel<<<(RELS * 256 * 2048 + 255) / 256, 256, 0, stream>>>(fW2, fW2bt, 256, 2048, (long long)RELS * 256 * 2048);
    cvt_transpose_bf16_kernel<<<(RELS * 2048 * 320 + 255) / 256, 256, 0, stream>>>(fW3, fW3bt, 2048, 320, (long long)RELS * 2048 * 320);

    // ---- d-branch (MFMA): z1d -> z2d -> dhead (uses z1bf buffer, freed before f-branch) ----
    {
        dim3 g1(256 / 128, S_SEEDS / 128, RELS);
        gemm_mfma_bf16<2, true><<<g1, 256, 0, stream>>>(
            hsbf, 0, HID, dW1bt, 256LL * 64, db1, 256,
            z1bf, (long long)S_SEEDS * 256, 256, S_SEEDS, 256, HID);
        dim3 g2(1, S_SEEDS / 128, RELS);
        gemm_mfma_bf16<2, false><<<g2, 256, 0, stream>>>(
            z1bf, (long long)S_SEEDS * 256, 256, dW2bt, 32LL * 256, db2, 32,
            z2d, (long long)S_SEEDS * 32, 32, S_SEEDS, 32, 256);
        dhead_kernel<<<(RELS * S_SEEDS + 255) / 256, 256, 0, stream>>>(z2d, dW3, db3, out);
    }

    // ---- f-branch (MFMA): z1 -> chunked (fW2, fW3) ----
    {
        dim3 grid(256 / 128, S_SEEDS / 128, RELS);
        gemm_mfma_bf16<1, true><<<grid, 256, 0, stream>>>(
            hsbf, 0, HID, fW1bt, 256LL * 64, fb1, 256,
            z1bf, (long long)S_SEEDS * 256, 256, S_SEEDS, 256, HID);
    }
    for (int c = 0; c < S_SEEDS / S_CH; c++) {
        long long s0 = (long long)c * S_CH;
        dim3 g2(2048 / 128, S_CH / 128, RELS);
        gemm_mfma_bf16<1, true><<<g2, 256, 0, stream>>>(
            z1bf + s0 * 256, (long long)S_SEEDS * 256, 256,
            fW2bt, 2048LL * 256, fb2, 2048,
            z2bf, (long long)S_CH * 2048, 2048, S_CH, 2048, 256);
        dim3 g3((320 + 127) / 128, S_CH / 128, RELS);
        gemm_mfma_bf16<3, false><<<g3, 256, 0, stream>>>(
            z2bf, (long long)S_CH * 2048, 2048,
            fW3bt, 320LL * 2048, fb3, 320,
            out + s0 * OUT_COLS + 1, (long long)S_SEEDS * OUT_COLS, OUT_COLS,
            S_CH, 320, 2048);
    }
}

// Round 5
// 1139.008 us; speedup vs baseline: 3.3109x; 1.0245x over previous
//
#include <hip/hip_runtime.h>
#include <math.h>

// Problem constants (match reference)
#define N_NODES 50000
#define N_EDGES 800000
#define RELS    3
#define HID     64
#define S_SEEDS 8192
#define OUT_COLS 321   // 1 (pred_missing) + 320 (pred_feat)
#define S_CH    2048   // seed-chunk for the 2048-wide f-branch hidden layer
#define NPITCH  50048  // per-relation pitch for counts/rowptr/cursor/invdeg
#define NB_SCAN 196    // ceil(50000/256)

typedef __attribute__((ext_vector_type(8))) short v8s;   // 8 bf16 in 4 VGPRs
typedef __attribute__((ext_vector_type(4))) float v4f;   // MFMA accumulator

__device__ __forceinline__ unsigned short f32_to_bf16(float f) {
    unsigned int u = __float_as_uint(f);
    unsigned int r = u + 0x7FFFu + ((u >> 16) & 1u);   // round-to-nearest-even
    return (unsigned short)(r >> 16);
}
__device__ __forceinline__ float bf16_to_f32(unsigned short u) {
    return __uint_as_float(((unsigned int)u) << 16);
}

// ---------------------------------------------------------------------------
// bf16 MFMA GEMM: C = act(A @ Bt^T + bias) [+ noise]
// A : M x K bf16 row-major (lda); Bt: N x K bf16 (B pre-transposed)
// Block 256 = 4 waves; tile 128x128; BK=32. Staging: 2 threads/row x 32 B.
// ACT: 0=none 1=relu 2=leaky(0.01) 3=tanh. noise (f32, stride ldc) added after act.
// ---------------------------------------------------------------------------
template<int ACT, bool OUT_BF16>
__global__ __launch_bounds__(256) void gemm_mfma_bf16(
    const unsigned short* __restrict__ A, long long sAb, int lda,
    const unsigned short* __restrict__ Bt, long long sBb,
    const float* __restrict__ bias, long long sBiasb,
    void* __restrict__ Cv, long long sCb, int ldc,
    const float* __restrict__ noise,
    int M, int Nc, int K)
{
    __shared__ __align__(16) unsigned short As[128][40];
    __shared__ __align__(16) unsigned short Bs[128][40];

    const int r = blockIdx.z;
    A  += (long long)r * sAb;
    Bt += (long long)r * sBb;
    const float* brow = bias ? bias + (long long)r * sBiasb : nullptr;

    const int tid  = threadIdx.x;
    const int wave = tid >> 6, lane = tid & 63;
    const int quad = lane >> 4, l16 = lane & 15;
    const int wrow = (wave >> 1) * 64, wcol = (wave & 1) * 64;
    const int row0 = blockIdx.y * 128, col0 = blockIdx.x * 128;

    v4f acc[4][4] = {};

    const int srow = tid >> 1;            // 0..127
    const int ecol = (tid & 1) * 16;      // each thread stages 16 bf16 = 32 B

    for (int k0 = 0; k0 < K; k0 += 32) {
        int gr = row0 + srow;
        int4 a0 = make_int4(0, 0, 0, 0), a1 = make_int4(0, 0, 0, 0);
        if (gr < M) {
            const unsigned short* ap = A + (long long)gr * lda + k0 + ecol;
            a0 = *(const int4*)(ap);
            a1 = *(const int4*)(ap + 8);
        }
        *(int4*)(&As[srow][ecol])     = a0;
        *(int4*)(&As[srow][ecol + 8]) = a1;

        int gn = col0 + srow;
        int4 b0 = make_int4(0, 0, 0, 0), b1 = make_int4(0, 0, 0, 0);
        if (gn < Nc) {
            const unsigned short* bp = Bt + (long long)gn * K + k0 + ecol;
            b0 = *(const int4*)(bp);
            b1 = *(const int4*)(bp + 8);
        }
        *(int4*)(&Bs[srow][ecol])     = b0;
        *(int4*)(&Bs[srow][ecol + 8]) = b1;
        __syncthreads();

        v8s af[4], bfr[4];
#pragma unroll
        for (int i = 0; i < 4; i++)
            af[i] = *(const v8s*)(&As[wrow + i * 16 + l16][quad * 8]);
#pragma unroll
        for (int j = 0; j < 4; j++)
            bfr[j] = *(const v8s*)(&Bs[wcol + j * 16 + l16][quad * 8]);
#pragma unroll
        for (int i = 0; i < 4; i++)
#pragma unroll
            for (int j = 0; j < 4; j++)
                acc[i][j] = __builtin_amdgcn_mfma_f32_16x16x32_bf16(af[i], bfr[j], acc[i][j], 0, 0, 0);
        __syncthreads();
    }

    float* Cf = (float*)Cv + (long long)r * sCb;
    unsigned short* Cb = (unsigned short*)Cv + (long long)r * sCb;
#pragma unroll
    for (int i = 0; i < 4; i++) {
#pragma unroll
        for (int j = 0; j < 4; j++) {
            int gc = col0 + wcol + j * 16 + l16;
            if (gc >= Nc) continue;
            float bv = brow ? brow[gc] : 0.f;
#pragma unroll
            for (int t = 0; t < 4; t++) {
                int gr = row0 + wrow + i * 16 + quad * 4 + t;
                if (gr >= M) continue;
                float v = acc[i][j][t] + bv;
                if (ACT == 1)      v = fmaxf(v, 0.f);
                else if (ACT == 2) v = (v > 0.f) ? v : 0.01f * v;
                else if (ACT == 3) v = tanhf(v);
                if (noise) v += noise[(long long)gr * ldc + gc];
                if (OUT_BF16) Cb[(long long)gr * ldc + gc] = f32_to_bf16(v);
                else          Cf[(long long)gr * ldc + gc] = v;
            }
        }
    }
}

// ---------------------------------------------------------------------------
// Prep kernels
// ---------------------------------------------------------------------------
__global__ void cvt_f32_bf16_kernel(const float* __restrict__ src,
                                    unsigned short* __restrict__ dst, long long n)
{
    long long i = (long long)blockIdx.x * blockDim.x + threadIdx.x;
    if (i < n) dst[i] = f32_to_bf16(src[i]);
}

// Tiled transpose+cvt: src (R, K, N) f32 -> dst (R, N, K) bf16. Coalesced both sides.
__global__ __launch_bounds__(256) void transpose_bf16_kernel(
    const float* __restrict__ src, unsigned short* __restrict__ dst, int K, int N)
{
    __shared__ float t[32][33];
    int r = blockIdx.z;
    src += (long long)r * K * N;
    dst += (long long)r * K * N;
    int n0 = blockIdx.x * 32, k0 = blockIdx.y * 32;
    int tx = threadIdx.x & 31, ty = threadIdx.x >> 5;   // (32, 8)
#pragma unroll
    for (int i = 0; i < 32; i += 8) {
        int k = k0 + ty + i, n = n0 + tx;
        if (k < K && n < N) t[ty + i][tx] = src[(long long)k * N + n];
    }
    __syncthreads();
#pragma unroll
    for (int i = 0; i < 32; i += 8) {
        int n = n0 + ty + i, k = k0 + tx;
        if (n < N && k < K) dst[(long long)n * K + k] = f32_to_bf16(t[tx][ty + i]);
    }
}

// ---------------------------------------------------------------------------
// CSR build: histogram -> block scan (3 kernels) -> cursor fill
// counts/rowptr/cursor/invdeg are (RELS, NPITCH); csr_src is (RELS, N_EDGES)
// ---------------------------------------------------------------------------
__global__ void hist3_kernel(const int* __restrict__ d0, const int* __restrict__ d1,
                             const int* __restrict__ d2, int* __restrict__ counts)
{
    int rel = blockIdx.y;
    const int* dp = (rel == 0) ? d0 : (rel == 1) ? d1 : d2;
    int e = blockIdx.x * blockDim.x + threadIdx.x;
    if (e < N_EDGES) atomicAdd(&counts[rel * NPITCH + dp[e]], 1);
}

__global__ void scan1_kernel(const int* __restrict__ counts,
                             int* __restrict__ rowptr, int* __restrict__ partials)
{
    __shared__ int sd[256];
    int rel = blockIdx.y, t = threadIdx.x;
    int i = blockIdx.x * 256 + t;
    int v = (i < N_NODES) ? counts[rel * NPITCH + i] : 0;
    sd[t] = v; __syncthreads();
    for (int off = 1; off < 256; off <<= 1) {
        int x = (t >= off) ? sd[t - off] : 0;
        __syncthreads();
        sd[t] += x;
        __syncthreads();
    }
    if (i < N_NODES) rowptr[rel * NPITCH + i] = sd[t] - v;   // local exclusive
    if (t == 255) partials[rel * 256 + blockIdx.x] = sd[255];
}

__global__ void scan2_kernel(int* __restrict__ partials)
{
    __shared__ int sd[256];
    int rel = blockIdx.y, t = threadIdx.x;
    int v = (t < NB_SCAN) ? partials[rel * 256 + t] : 0;
    sd[t] = v; __syncthreads();
    for (int off = 1; off < 256; off <<= 1) {
        int x = (t >= off) ? sd[t - off] : 0;
        __syncthreads();
        sd[t] += x;
        __syncthreads();
    }
    if (t < NB_SCAN) partials[rel * 256 + t] = sd[t] - v;    // exclusive
}

__global__ void scan3_kernel(const int* __restrict__ counts,
                             int* __restrict__ rowptr, const int* __restrict__ partials,
                             int* __restrict__ cursor, float* __restrict__ invdeg)
{
    int rel = blockIdx.y, t = threadIdx.x;
    int i = blockIdx.x * 256 + t;
    if (i < N_NODES) {
        int rp = rowptr[rel * NPITCH + i] + partials[rel * 256 + blockIdx.x];
        rowptr[rel * NPITCH + i] = rp;
        cursor[rel * NPITCH + i] = rp;
        int c = counts[rel * NPITCH + i];
        invdeg[rel * NPITCH + i] = 1.0f / fmaxf((float)c, 1.0f);
    }
    if (i == 0) rowptr[rel * NPITCH + N_NODES] = N_EDGES;
}

__global__ void fill3_kernel(const int* __restrict__ s0, const int* __restrict__ d0,
                             const int* __restrict__ s1, const int* __restrict__ d1,
                             const int* __restrict__ s2, const int* __restrict__ d2,
                             int* __restrict__ cursor, int* __restrict__ csr_src)
{
    int rel = blockIdx.y;
    const int* sp = (rel == 0) ? s0 : (rel == 1) ? s1 : s2;
    const int* dp = (rel == 0) ? d0 : (rel == 1) ? d1 : d2;
    int e = blockIdx.x * blockDim.x + threadIdx.x;
    if (e >= N_EDGES) return;
    int d = dp[e];
    int pos = atomicAdd(&cursor[rel * NPITCH + d], 1);
    csr_src[(long long)rel * N_EDGES + pos] = sp[e];
}

// ---------------------------------------------------------------------------
// CSR gather (bf16 features): one wave per (node, relation); lane = feature.
// agg[d][r*64 + lane] = bf16( invdeg[r][d] * sum_{edges r: s->d} feat[s][lane] )
// ---------------------------------------------------------------------------
__global__ __launch_bounds__(256) void gather_bf16_kernel(
    const unsigned short* __restrict__ feat,   // (*, 64) bf16
    const int* __restrict__ rowptr,            // (RELS, NPITCH)
    const int* __restrict__ csr_src,           // (RELS, N_EDGES)
    const float* __restrict__ invdeg,          // (RELS, NPITCH)
    unsigned short* __restrict__ agg,          // (M, 192) bf16
    int M)
{
    int w = (blockIdx.x * 256 + threadIdx.x) >> 6;
    int lane = threadIdx.x & 63;
    if (w >= M * RELS) return;
    int r = w % RELS, d = w / RELS;
    int rp0 = rowptr[r * NPITCH + d];
    int rp1 = rowptr[r * NPITCH + d + 1];
    const int* cp = csr_src + (long long)r * N_EDGES;
    float acc0 = 0.f, acc1 = 0.f;
    int i = rp0;
    for (; i + 1 < rp1; i += 2) {
        int s0 = cp[i], s1 = cp[i + 1];
        acc0 += bf16_to_f32(feat[(long long)s0 * HID + lane]);
        acc1 += bf16_to_f32(feat[(long long)s1 * HID + lane]);
    }
    if (i < rp1) acc0 += bf16_to_f32(feat[(long long)cp[i] * HID + lane]);
    agg[(long long)d * (RELS * HID) + r * HID + lane] =
        f32_to_bf16((acc0 + acc1) * invdeg[r * NPITCH + d]);
}

// ---------------------------------------------------------------------------
// d-branch final head: out[r,s,0] = relu(z2d[r,s,:] . dW3[r] + db3[r])
// ---------------------------------------------------------------------------
__global__ void dhead_kernel(const float* __restrict__ z2d,
                             const float* __restrict__ dW3,
                             const float* __restrict__ db3,
                             float* __restrict__ out)
{
    int idx = blockIdx.x * blockDim.x + threadIdx.x;
    if (idx >= RELS * S_SEEDS) return;
    int r = idx / S_SEEDS;
    const float* zp = z2d + (long long)idx * 32;
    const float* wp = dW3 + r * 32;
    float acc = db3[r];
#pragma unroll
    for (int k = 0; k < 32; k++) acc += zp[k] * wp[k];
    out[(long long)idx * OUT_COLS] = fmaxf(acc, 0.f);
}

// ---------------------------------------------------------------------------
extern "C" void kernel_launch(void* const* d_in, const int* in_sizes, int n_in,
                              void* d_out, int out_size, void* d_ws, size_t ws_size,
                              hipStream_t stream)
{
    const float* x     = (const float*)d_in[0];
    const float* noise = (const float*)d_in[1];
    // d_in[2] = seeds: only its shape matters (S=8192); unused.
    const int* srcs[RELS] = { (const int*)d_in[3], (const int*)d_in[5], (const int*)d_in[7] };
    const int* dsts[RELS] = { (const int*)d_in[4], (const int*)d_in[6], (const int*)d_in[8] };
    const float* Wc1  = (const float*)d_in[9];   // (3,64,64) == stacked (192,64)
    const float* bc1  = (const float*)d_in[10];
    const float* Wc2  = (const float*)d_in[11];
    const float* bc2  = (const float*)d_in[12];
    const float* Wlin = (const float*)d_in[13];
    const float* blin = (const float*)d_in[14];
    const float* dW1  = (const float*)d_in[15];
    const float* db1  = (const float*)d_in[16];
    const float* dW2  = (const float*)d_in[17];
    const float* db2  = (const float*)d_in[18];
    const float* dW3  = (const float*)d_in[19];
    const float* db3  = (const float*)d_in[20];
    const float* fW1  = (const float*)d_in[21];
    const float* fb1  = (const float*)d_in[22];
    const float* fW2  = (const float*)d_in[23];
    const float* fb2  = (const float*)d_in[24];
    const float* fW3  = (const float*)d_in[25];
    const float* fb3  = (const float*)d_in[26];
    float* out = (float*)d_out;
    float* w   = (float*)d_ws;

    // ---- workspace layout (4-byte units; ~72 MB total, all 16B-aligned) ----
    int*   counts  = (int*)w;                              // 150,144
    int*   rowptr  = (int*)(w + 150144);                   // 150,144
    int*   cursor  = (int*)(w + 300288);                   // 150,144
    int*   partials= (int*)(w + 450432);                   // 1,024
    float* invdeg  = w + 451456;                           // 150,144
    int*   csr_src = (int*)(w + 601600);                   // 2,400,000
    // REGION_A (6,291,456 f): aggx_bf (gather1 out, dead after conv1) then z2bf
    unsigned short* aggx_bf = (unsigned short*)(w + 3001600);  // 50000*192 bf16
    unsigned short* z2bf    = (unsigned short*)(w + 3001600);  // 3*2048*2048 bf16
    // REGION_B (3,145,728 f): xbf (dead after gather1) then z1bf
    unsigned short* xbf  = (unsigned short*)(w + 9293056);     // 50000*64 bf16
    unsigned short* z1bf = (unsigned short*)(w + 9293056);     // 3*8192*256 bf16
    unsigned short* h1bf   = (unsigned short*)(w + 12438784);  // 50000*64 bf16
    unsigned short* agg2bf = (unsigned short*)(w + 14038784);  // 8192*192 bf16
    unsigned short* h2sbf  = (unsigned short*)(w + 14825216);  // 8192*64 bf16
    unsigned short* hsbf   = (unsigned short*)(w + 15087360);  // 8192*64 bf16
    float* z2d             = w + 15349504;                     // 3*8192*32 f32
    unsigned short* WcT1   = (unsigned short*)(w + 16135936);  // (64,192) bf16
    unsigned short* WcT2   = (unsigned short*)(w + 16142080);  // (64,192) bf16
    unsigned short* WlinT  = (unsigned short*)(w + 16148224);  // (64,64) bf16
    unsigned short* dW1bt  = (unsigned short*)(w + 16150272);  // (3,256,64) bf16
    unsigned short* dW2bt  = (unsigned short*)(w + 16174848);  // (3,32,256) bf16
    unsigned short* fW1bt  = (unsigned short*)(w + 16187136);  // (3,256,64) bf16
    unsigned short* fW2bt  = (unsigned short*)(w + 16211712);  // (3,2048,256) bf16
    unsigned short* fW3bt  = (unsigned short*)(w + 16998144);  // (3,320,2048) bf16

    // ---- CSR build (shared by both conv layers) ----
    hipMemsetAsync(counts, 0, (size_t)RELS * NPITCH * sizeof(int), stream);
    {
        dim3 ge((N_EDGES + 255) / 256, RELS);
        hist3_kernel<<<ge, 256, 0, stream>>>(dsts[0], dsts[1], dsts[2], counts);
        dim3 gs1(NB_SCAN, RELS);
        scan1_kernel<<<gs1, 256, 0, stream>>>(counts, rowptr, partials);
        scan2_kernel<<<dim3(1, RELS), 256, 0, stream>>>(partials);
        scan3_kernel<<<gs1, 256, 0, stream>>>(counts, rowptr, partials, cursor, invdeg);
        fill3_kernel<<<ge, 256, 0, stream>>>(srcs[0], dsts[0], srcs[1], dsts[1],
                                             srcs[2], dsts[2], cursor, csr_src);
    }

    // ---- weight prep (tiled transpose+cvt, coalesced) ----
    cvt_f32_bf16_kernel<<<(N_NODES * HID + 255) / 256, 256, 0, stream>>>(x, xbf, (long long)N_NODES * HID);
    transpose_bf16_kernel<<<dim3(2, 6, 1), 256, 0, stream>>>(Wc1, WcT1, 192, 64);
    transpose_bf16_kernel<<<dim3(2, 6, 1), 256, 0, stream>>>(Wc2, WcT2, 192, 64);
    transpose_bf16_kernel<<<dim3(2, 2, 1), 256, 0, stream>>>(Wlin, WlinT, 64, 64);
    transpose_bf16_kernel<<<dim3(8, 2, RELS), 256, 0, stream>>>(dW1, dW1bt, 64, 256);
    transpose_bf16_kernel<<<dim3(1, 8, RELS), 256, 0, stream>>>(dW2, dW2bt, 256, 32);
    transpose_bf16_kernel<<<dim3(8, 2, RELS), 256, 0, stream>>>(fW1, fW1bt, 64, 256);
    transpose_bf16_kernel<<<dim3(64, 8, RELS), 256, 0, stream>>>(fW2, fW2bt, 256, 2048);
    transpose_bf16_kernel<<<dim3(10, 64, RELS), 256, 0, stream>>>(fW3, fW3bt, 2048, 320);

    // ---- conv layer 1: gather xbf -> aggx_bf (50000x192), MFMA -> h1bf ----
    gather_bf16_kernel<<<(N_NODES * RELS * 64 + 255) / 256, 256, 0, stream>>>(
        xbf, rowptr, csr_src, invdeg, aggx_bf, N_NODES);
    gemm_mfma_bf16<1, true><<<dim3(1, (N_NODES + 127) / 128, 1), 256, 0, stream>>>(
        aggx_bf, 0, RELS * HID, WcT1, 0, bc1, 0,
        h1bf, 0, HID, nullptr, N_NODES, HID, RELS * HID);

    // ---- conv layer 2 (rows < S only): gather h1bf -> agg2bf, MFMA -> h2sbf ----
    gather_bf16_kernel<<<(S_SEEDS * RELS * 64 + 255) / 256, 256, 0, stream>>>(
        h1bf, rowptr, csr_src, invdeg, agg2bf, S_SEEDS);
    gemm_mfma_bf16<1, true><<<dim3(1, S_SEEDS / 128, 1), 256, 0, stream>>>(
        agg2bf, 0, RELS * HID, WcT2, 0, bc2, 0,
        h2sbf, 0, HID, nullptr, S_SEEDS, HID, RELS * HID);

    // ---- hs = leaky(h2s @ Wlin + blin) + noise[:S]  (MFMA, bf16 out) ----
    gemm_mfma_bf16<2, true><<<dim3(1, S_SEEDS / 128, 1), 256, 0, stream>>>(
        h2sbf, 0, HID, WlinT, 0, blin, 0,
        hsbf, 0, HID, noise, S_SEEDS, HID, HID);

    // ---- d-branch (MFMA): z1 -> z2d -> dhead ----
    gemm_mfma_bf16<2, true><<<dim3(2, S_SEEDS / 128, RELS), 256, 0, stream>>>(
        hsbf, 0, HID, dW1bt, 256LL * 64, db1, 256,
        z1bf, (long long)S_SEEDS * 256, 256, nullptr, S_SEEDS, 256, HID);
    gemm_mfma_bf16<2, false><<<dim3(1, S_SEEDS / 128, RELS), 256, 0, stream>>>(
        z1bf, (long long)S_SEEDS * 256, 256, dW2bt, 32LL * 256, db2, 32,
        z2d, (long long)S_SEEDS * 32, 32, nullptr, S_SEEDS, 32, 256);
    dhead_kernel<<<(RELS * S_SEEDS + 255) / 256, 256, 0, stream>>>(z2d, dW3, db3, out);

    // ---- f-branch (MFMA): z1 -> chunked (fW2, fW3) ----
    gemm_mfma_bf16<1, true><<<dim3(2, S_SEEDS / 128, RELS), 256, 0, stream>>>(
        hsbf, 0, HID, fW1bt, 256LL * 64, fb1, 256,
        z1bf, (long long)S_SEEDS * 256, 256, nullptr, S_SEEDS, 256, HID);
    for (int c = 0; c < S_SEEDS / S_CH; c++) {
        long long s0 = (long long)c * S_CH;
        gemm_mfma_bf16<1, true><<<dim3(2048 / 128, S_CH / 128, RELS), 256, 0, stream>>>(
            z1bf + s0 * 256, (long long)S_SEEDS * 256, 256,
            fW2bt, 2048LL * 256, fb2, 2048,
            z2bf, (long long)S_CH * 2048, 2048, nullptr, S_CH, 2048, 256);
        gemm_mfma_bf16<3, false><<<dim3((320 + 127) / 128, S_CH / 128, RELS), 256, 0, stream>>>(
            z2bf, (long long)S_CH * 2048, 2048,
            fW3bt, 320LL * 2048, fb3, 320,
            out + s0 * OUT_COLS + 1, (long long)S_SEEDS * OUT_COLS, OUT_COLS,
            nullptr, S_CH, 320, 2048);
    }
}